// Round 10
// baseline (22.721 us; speedup 1.0000x reference)
//
#include <hip/hip_runtime.h>

#define B_ 4
#define C_ 64
#define H_ 128
#define W_ 128
#define R_ 4            // outputs per thread (vertical strip)
#define BROWS 8         // output rows per block
#define LROWS 12        // BROWS + 4 halo rows
#define LPITCH 136      // floats per LDS row (544 B = 16B multiple); data at [2..129]
#define LOG2E 1.44269504088896340736f

typedef float v2f __attribute__((ext_vector_type(2)));

__device__ __forceinline__ v2f exp2v(v2f x) {
    return (v2f){ __builtin_amdgcn_exp2f(x.x), __builtin_amdgcn_exp2f(x.y) };
}

// HALF=0: rel indexed by window row i (rel_h); HALF=1: by window col j (rel_w).
// All taps stream from zero-padded LDS: no masks, no clamps, no register window.
template<int HALF>
__device__ __forceinline__ void sa_strip(
    const float* __restrict__ lp,      // &lds[s*R_][x]
    const float* __restrict__ f1p, const float* __restrict__ relp,
    float* __restrict__ outp, int x, int y0)
{
    float rel5[5];                      // block-uniform -> scalar regs
    #pragma unroll
    for (int k = 0; k < 5; ++k) rel5[k] = relp[k];

    float q2[R_];
    #pragma unroll
    for (int r = 0; r < R_; ++r) q2[r] = f1p[(y0 + r) * W_ + x] * LOG2E;

    #pragma unroll
    for (int r = 0; r < R_; ++r) {
        const float q = q2[r];
        const v2f qv = {q, q};
        float pr[5];
        #pragma unroll
        for (int k = 0; k < 5; ++k) pr[k] = q * rel5[k];
        const v2f prA = {pr[0], pr[1]};
        const v2f prB = {pr[2], pr[3]};
        const float prC = pr[4];

        v2f s0 = {0.f,0.f}, s1 = {0.f,0.f}, d0 = {0.f,0.f}, d1 = {0.f,0.f};
        float lv[5];

        #pragma unroll
        for (int i = 0; i < 5; ++i) {
            const float* row = lp + (r + i) * LPITCH;   // LDS, zero-padded
            const v2f va = {row[0], row[1]};
            const v2f vb = {row[2], row[3]};
            lv[i] = row[4];
            const v2f pa = (HALF == 0) ? (v2f){pr[i], pr[i]} : prA;
            const v2f pb = (HALF == 0) ? (v2f){pr[i], pr[i]} : prB;
            const v2f p0 = exp2v(__builtin_elementwise_fma(va, qv, pa));
            s0 += p0; d0 = __builtin_elementwise_fma(p0, va, d0);
            const v2f p1 = exp2v(__builtin_elementwise_fma(vb, qv, pb));
            s1 += p1; d1 = __builtin_elementwise_fma(p1, vb, d1);
        }
        {   // leftover column j=4, rows (0,1)
            const v2f v  = {lv[0], lv[1]};
            const v2f pp = (HALF == 0) ? (v2f){pr[0], pr[1]} : (v2f){prC, prC};
            const v2f p  = exp2v(__builtin_elementwise_fma(v, qv, pp));
            s0 += p; d0 = __builtin_elementwise_fma(p, v, d0);
        }
        {   // rows (2,3)
            const v2f v  = {lv[2], lv[3]};
            const v2f pp = (HALF == 0) ? (v2f){pr[2], pr[3]} : (v2f){prC, prC};
            const v2f p  = exp2v(__builtin_elementwise_fma(v, qv, pp));
            s1 += p; d1 = __builtin_elementwise_fma(p, v, d1);
        }
        float ss, ds;
        {   // scalar tail: row 4, col 4
            const float pp = (HALF == 0) ? pr[4] : prC;
            const float p  = __builtin_amdgcn_exp2f(__builtin_fmaf(q, lv[4], pp));
            ss = p; ds = p * lv[4];
        }
        const v2f st = s0 + s1, dt = d0 + d1;
        outp[(y0 + r) * W_ + x] = (dt.x + dt.y + ds) * __builtin_amdgcn_rcpf(st.x + st.y + ss);
    }
}

__global__ __launch_bounds__(256) void sa_kernel(
    const float* __restrict__ f1, const float* __restrict__ f2,
    const float* __restrict__ relh, const float* __restrict__ relw,
    float* __restrict__ out)
{
    __shared__ float lds[LROWS][LPITCH];

    const int tid = threadIdx.x;
    const int blk = blockIdx.x;
    const int yb  = blk & (H_ / BROWS - 1);    // 16 y-blocks per image
    const int bc  = blk >> 4;
    const int c   = bc & (C_ - 1);
    const int b   = bc >> 6;
    const int ybase = yb * BROWS;

    const size_t img = (size_t)(b * C_ + c) * (H_ * W_);
    const float* f1p = f1 + img;
    const float* f2p = f2 + img;

    // ---- stage f2 rows [ybase-2, ybase+10) into LDS, zero borders baked in ----
    #pragma unroll
    for (int k = 0; k < 3; ++k) {
        const int idx = tid + k * 256;          // [0, 768): 12 rows x 64 float2
        const int row = idx >> 6;               // wave-uniform per k
        const int cx  = (idx & 63) * 2;
        const int gy  = ybase + row - 2;
        float2 val = {0.f, 0.f};
        if ((unsigned)gy < (unsigned)H_) val = *(const float2*)(f2p + gy * W_ + cx);
        *(float2*)&lds[row][2 + cx] = val;
    }
    if (tid < 2 * LROWS) {                      // x-halo zeros: cols [0,1] and [130,131]
        const int row = tid >> 1;
        *(float2*)&lds[row][(tid & 1) ? 130 : 0] = (float2){0.f, 0.f};
    }
    __syncthreads();

    const int x  = tid & (W_ - 1);
    const int s  = tid >> 7;                    // 0/1: upper/lower 4-row strip
    const int y0 = ybase + s * R_;
    const float* lp = &lds[s * R_][x];          // tap (r,i,j) = lp[(r+i)*LPITCH + j]

    const int c_out = (c & 7) * 8 + (c >> 3);   // einsum channel transpose
    float* outp = out + (size_t)(b * C_ + c_out) * (H_ * W_);

    if (c < C_ / 2) sa_strip<0>(lp, f1p, relh + c * 5, outp, x, y0);
    else            sa_strip<1>(lp, f1p, relw + (c - C_ / 2) * 5, outp, x, y0);
}

extern "C" void kernel_launch(void* const* d_in, const int* in_sizes, int n_in,
                              void* d_out, int out_size, void* d_ws, size_t ws_size,
                              hipStream_t stream) {
    const float* f1   = (const float*)d_in[0];
    const float* f2   = (const float*)d_in[1];
    const float* relh = (const float*)d_in[2];
    const float* relw = (const float*)d_in[3];
    float* out = (float*)d_out;

    const int grid = B_ * C_ * (H_ / BROWS);   // 4096 blocks
    sa_kernel<<<grid, 256, 0, stream>>>(f1, f2, relh, relw, out);
}